// Round 17
// baseline (624.270 us; speedup 1.0000x reference)
//
#include <hip/hip_runtime.h>
#include <hip/hip_bf16.h>
#include <math.h>

#define TT 128      // time steps
#define CC 256      // channels
#define MAXLEN 80
#define KSTEPS 24   // 3 taps * 8 k-blocks of 32
#define SLOTS 68    // rows base-2 .. base+65 ; slot = (row-base)+2
#define NCH16 32    // 16B chunks (8 f16) per 256-ch row

typedef __attribute__((ext_vector_type(8))) _Float16 half8v;  // 8 f16 = 4 VGPR
typedef __attribute__((ext_vector_type(2))) _Float16 half2v;
typedef __attribute__((ext_vector_type(4))) float f32x4;

#define MSCALE 4096.0f       // 2^12: keeps m-plane out of f16 denormal range
#define MINV   (1.0f/4096.0f)

__device__ __forceinline__ int chunkidx(int slot, int c16) {
    return slot * NCH16 + (c16 ^ (slot & 7));
}

// h = RTZ f16 pair (pkrtz); m = RTNE f16 of (x-h)*4096 (exact residual capture).
__device__ __forceinline__ void split2(float x0, float x1, half2v& h, half2v& m) {
    h = __builtin_bit_cast(half2v, __builtin_amdgcn_cvt_pkrtz(x0, x1));
    m.x = (_Float16)fmaf((float)h.x, -MSCALE, x0 * MSCALE);
    m.y = (_Float16)fmaf((float)h.y, -MSCALE, x1 * MSCALE);
}

// ---------------- prep: split conv weights into f16 h/m planes (m scaled 2^12,
// both RTNE) in MFMA B-fragment order. frag = (((cv*3+tap)*8+kk2)*2+plane);
// entry idx = (frag*16 + nfg)*64 + lane; each entry = 8 f16 (k-contig).
__global__ void va_prep(const float* __restrict__ w1, const float* __restrict__ w2,
                        half8v* __restrict__ wsB)
{
    const int idx = blockIdx.x * 256 + threadIdx.x;   // 0 .. 98303
    const int lane = idx & 63;
    int q = idx >> 6;
    const int nfg = q & 15;   q >>= 4;
    const int plane = q & 1;  q >>= 1;
    const int kk2 = q & 7;    q >>= 3;
    const int tap = q % 3;
    const int cv  = q / 3;
    const float* w = cv ? w2 : w1;
    const int co  = nfg * 16 + (lane & 15);
    const int ci0 = kk2 * 32 + (lane >> 4) * 8;
    half8v out;
    #pragma unroll
    for (int j = 0; j < 8; ++j) {
        const float x = w[tap * (CC * CC) + (ci0 + j) * CC + co];
        const _Float16 h = (_Float16)x;           // RTNE
        if (plane == 0) out[j] = h;
        else            out[j] = (_Float16)((x - (float)h) * MSCALE);
    }
    wsB[idx] = out;
}

// ---------------- conv kernel: 2 WGs per batch, 64 rows each, 4 waves.
// Wave w owns cols [w*64, w*64+64) (nf=4). conv1 computes x1 rows
// base-1..base+64 via frags {-1,15,31,47,49}; dup rows write identical bits.
__global__ __launch_bounds__(256, 2)
void va_conv(const float* __restrict__ enc,
             const float* __restrict__ b1g, const float* __restrict__ b2g,
             const float* __restrict__ gg,  const float* __restrict__ bbg,
             const float* __restrict__ dwg, const float* __restrict__ dbg,
             const half8v* __restrict__ wsB,
             int* __restrict__ durG)
{
    __shared__ half8v P[2][SLOTS * NCH16];   // 69,632 B
    __shared__ float sumS[4][80];
    __shared__ float sumQ[4][80];
    __shared__ float muS[80];
    __shared__ float rsS[80];
    __shared__ float dsum[4][64];

    const int bb   = blockIdx.x;
    const int b    = bb >> 1;
    const int base = (bb & 1) << 6;     // 0 or 64
    const int tid  = threadIdx.x;
    const int wid  = tid >> 6;          // 0..3
    const int lane = tid & 63;
    const int l15  = lane & 15;
    const int lg   = lane >> 4;
    const int NGc  = wid * 64;          // col base

    // One-time phase stagger: under both plausible dispatch models (linear,
    // XCD round-robin), co-resident slot-mates differ by 256 in blockIdx.
    // Sleeping ONE WG of each first-cohort pair (~40K cyc) anti-phases the
    // pair; later WGs inherit the offset via staggered slot completions.
    if (bb >= 256 && bb < 512) {
        #pragma unroll
        for (int i = 0; i < 5; ++i) __builtin_amdgcn_s_sleep(127);
    }

    const f32x4* encB4 = reinterpret_cast<const f32x4*>(enc) + (size_t)b * (TT * 64);

    // ---- stage enc rows base-2..base+65: NORMAL loads (keep L3 warm for
    // the gather pass), 2-deep software pipeline ----
    {
        const f32x4 z4 = {0.f, 0.f, 0.f, 0.f};
        f32x4 pa[2] = {z4, z4}, pb[2] = {z4, z4};
        {
            const int m2 = tid;
            const int ra = base + (m2 >> 5) - 2;
            if (ra >= 0 && ra < TT) {
                const f32x4* src = encB4 + ra * 64 + (m2 & 31) * 2;
                pa[0] = src[0];
                pb[0] = src[1];
            }
        }
        #pragma unroll
        for (int it = 0; it < 9; ++it) {
            const int nxt = it + 1;
            if (nxt < 9) {
                const int m2 = tid + nxt * 256;
                pa[nxt & 1] = z4; pb[nxt & 1] = z4;
                if (m2 < SLOTS * NCH16) {
                    const int ra = base + (m2 >> 5) - 2;
                    if (ra >= 0 && ra < TT) {
                        const f32x4* src = encB4 + ra * 64 + (m2 & 31) * 2;
                        pa[nxt & 1] = src[0];
                        pb[nxt & 1] = src[1];
                    }
                }
            }
            const int m2 = tid + it * 256;
            if (m2 < SLOTS * NCH16) {
                const f32x4 v0 = pa[it & 1], v1 = pb[it & 1];
                half8v h8, m8;
                half2v hp, mp;
                split2(v0.x, v0.y, hp, mp); h8[0]=hp.x; h8[1]=hp.y; m8[0]=mp.x; m8[1]=mp.y;
                split2(v0.z, v0.w, hp, mp); h8[2]=hp.x; h8[3]=hp.y; m8[2]=mp.x; m8[3]=mp.y;
                split2(v1.x, v1.y, hp, mp); h8[4]=hp.x; h8[5]=hp.y; m8[4]=mp.x; m8[5]=mp.y;
                split2(v1.z, v1.w, hp, mp); h8[6]=hp.x; h8[7]=hp.y; m8[6]=mp.x; m8[7]=mp.y;
                const int ci = chunkidx(m2 >> 5, m2 & 31);
                P[0][ci] = h8;
                P[1][ci] = m8;
            }
        }
    }
    __syncthreads();

    float gv[4], bvv[4];
    #pragma unroll
    for (int nf = 0; nf < 4; ++nf) {
        gv[nf]  = gg[NGc + nf * 16 + l15];
        bvv[nf] = bbg[NGc + nf * 16 + l15];
    }

    f32x4 accH[5][4];
    f32x4 accM[5][4];

    // ================= conv1: 5 frags {-1,15,31,47,49}, dbuf B =========
    {
        #pragma unroll
        for (int nf = 0; nf < 4; ++nf) {
            const float bz = b1g[NGc + nf * 16 + l15];
            const f32x4 b4 = {bz, bz, bz, bz};
            const f32x4 z4 = {0.f, 0.f, 0.f, 0.f};
            #pragma unroll
            for (int mf = 0; mf < 5; ++mf) { accH[mf][nf] = b4; accM[mf][nf] = z4; }
        }
        half8v B0[8], B1[8];   // [plane*4 + nf]
        auto loadB1 = [&](half8v (&Bp)[8], int ks) {
            const int tap = ks >> 3, kk2 = ks & 7;
            const int fb = (tap * 8 + kk2) * 2;          // cv=0
            #pragma unroll
            for (int p = 0; p < 2; ++p)
                #pragma unroll
                for (int nf = 0; nf < 4; ++nf)
                    Bp[p * 4 + nf] = wsB[(size_t)((fb + p) * 16 + (wid * 4 + nf)) * 64 + lane];
        };
        auto doK1 = [&](const half8v (&Bp)[8], int ks) {
            const int tap = ks >> 3, kk2 = ks & 7;
            #pragma unroll
            for (int mf = 0; mf < 5; ++mf) {
                constexpr int F1[5] = {-1, 15, 31, 47, 49};
                const int slot = F1[mf] + l15 + tap + 1;   // (row-1+tap)+2
                const int ci = chunkidx(slot, kk2 * 4 + lg);
                const half8v Ah = P[0][ci];
                const half8v Am = P[1][ci];
                __builtin_amdgcn_s_setprio(1);             // T5: favor MFMA wave
                #pragma unroll
                for (int nf = 0; nf < 4; ++nf) {
                    accH[mf][nf] = __builtin_amdgcn_mfma_f32_16x16x32_f16(Ah, Bp[nf],     accH[mf][nf], 0, 0, 0);
                    accM[mf][nf] = __builtin_amdgcn_mfma_f32_16x16x32_f16(Ah, Bp[4 + nf], accM[mf][nf], 0, 0, 0);
                    accM[mf][nf] = __builtin_amdgcn_mfma_f32_16x16x32_f16(Am, Bp[nf],     accM[mf][nf], 0, 0, 0);
                }
                __builtin_amdgcn_s_setprio(0);
            }
        };
        loadB1(B0, 0);
        #pragma unroll 1
        for (int ks = 0; ks < KSTEPS; ks += 2) {
            loadB1(B1, ks + 1);
            doK1(B0, ks);
            if (ks + 2 < KSTEPS) loadB1(B0, ks + 2);
            doK1(B1, ks + 1);
        }
        // combine + relu
        #pragma unroll
        for (int mf = 0; mf < 5; ++mf)
            #pragma unroll
            for (int nf = 0; nf < 4; ++nf) {
                f32x4 v;
                #pragma unroll
                for (int e = 0; e < 4; ++e)
                    v[e] = fmaxf(fmaf(accM[mf][nf][e], MINV, accH[mf][nf][e]), 0.f);
                accH[mf][nf] = v;
            }
        // LN single-pass stats (rows idx = row+1 in [0,65]; dup rows write
        // bitwise-identical values -> benign)
        constexpr int F1c[5] = {-1, 15, 31, 47, 49};
        #pragma unroll
        for (int mf = 0; mf < 5; ++mf)
            #pragma unroll
            for (int r = 0; r < 4; ++r) {
                float s = (accH[mf][0][r] + accH[mf][1][r]) + (accH[mf][2][r] + accH[mf][3][r]);
                float q = accH[mf][0][r] * accH[mf][0][r];
                q = fmaf(accH[mf][1][r], accH[mf][1][r], q);
                q = fmaf(accH[mf][2][r], accH[mf][2][r], q);
                q = fmaf(accH[mf][3][r], accH[mf][3][r], q);
                #pragma unroll
                for (int o = 1; o < 16; o <<= 1) {
                    s += __shfl_xor(s, o, 64);
                    q += __shfl_xor(q, o, 64);
                }
                if (l15 == 0) {
                    const int idx = F1c[mf] + lg * 4 + r + 1;
                    sumS[wid][idx] = s;
                    sumQ[wid][idx] = q;
                }
            }
        __syncthreads();
        // redundant per-wave mu/rs for all 66 rows (identical bits from all
        // writers; within-wave RAW ordered by lgkmcnt) — validated R8/R9
        for (int i = lane; i < 66; i += 64) {
            const float S = (sumS[0][i] + sumS[1][i]) + (sumS[2][i] + sumS[3][i]);
            const float Q = (sumQ[0][i] + sumQ[1][i]) + (sumQ[2][i] + sumQ[3][i]);
            const float mu = S * (1.f / 256.f);
            const float var = fmaf(-mu, mu, Q * (1.f / 256.f));
            muS[i] = mu;
            rsS[i] = 1.0f / sqrtf(var + 1e-6f);
        }
        // normalize + writeback x1 (h/m planes); rows outside [0,TT) forced 0
        _Float16* Ph = (_Float16*)&P[0][0];
        _Float16* Pm = (_Float16*)&P[1][0];
        #pragma unroll
        for (int mf = 0; mf < 5; ++mf)
            #pragma unroll
            for (int r = 0; r < 4; ++r) {
                const int row = F1c[mf] + lg * 4 + r;
                const float mu = muS[row + 1];
                const float rs = rsS[row + 1];
                const bool valid = (base + row >= 0) && (base + row < TT);
                #pragma unroll
                for (int nf = 0; nf < 4; ++nf) {
                    float v = (accH[mf][nf][r] - mu) * rs * gv[nf] + bvv[nf];
                    if (!valid) v = 0.f;
                    const int col = NGc + nf * 16 + l15;
                    const int off = chunkidx(row + 2, col >> 3) * 8 + (col & 7);
                    const _Float16 h = (_Float16)v;   // RTNE
                    Ph[off] = h;
                    Pm[off] = (_Float16)fmaf((float)h, -MSCALE, v * MSCALE);
                }
            }
    }
    __syncthreads();

    // ================= conv2: 4 frags {0,16,32,48}, dbuf B ==============
    {
        #pragma unroll
        for (int nf = 0; nf < 4; ++nf) {
            const float bz = b2g[NGc + nf * 16 + l15];
            const f32x4 b4 = {bz, bz, bz, bz};
            const f32x4 z4 = {0.f, 0.f, 0.f, 0.f};
            #pragma unroll
            for (int mf = 0; mf < 4; ++mf) { accH[mf][nf] = b4; accM[mf][nf] = z4; }
        }
        half8v B0[8], B1[8];
        auto loadB = [&](half8v (&Bp)[8], int ks) {
            const int tap = ks >> 3, kk2 = ks & 7;
            const int fb = ((3 + tap) * 8 + kk2) * 2;    // cv=1
            #pragma unroll
            for (int p = 0; p < 2; ++p)
                #pragma unroll
                for (int nf = 0; nf < 4; ++nf)
                    Bp[p * 4 + nf] = wsB[(size_t)((fb + p) * 16 + (wid * 4 + nf)) * 64 + lane];
        };
        auto doK = [&](const half8v (&Bp)[8], int ks) {
            const int tap = ks >> 3, kk2 = ks & 7;
            #pragma unroll
            for (int mf = 0; mf < 4; ++mf) {
                const int slot = mf * 16 + l15 + tap + 1;
                const int ci = chunkidx(slot, kk2 * 4 + lg);
                const half8v Ah = P[0][ci];
                const half8v Am = P[1][ci];
                __builtin_amdgcn_s_setprio(1);             // T5
                #pragma unroll
                for (int nf = 0; nf < 4; ++nf) {
                    accH[mf][nf] = __builtin_amdgcn_mfma_f32_16x16x32_f16(Ah, Bp[nf],     accH[mf][nf], 0, 0, 0);
                    accM[mf][nf] = __builtin_amdgcn_mfma_f32_16x16x32_f16(Ah, Bp[4 + nf], accM[mf][nf], 0, 0, 0);
                    accM[mf][nf] = __builtin_amdgcn_mfma_f32_16x16x32_f16(Am, Bp[nf],     accM[mf][nf], 0, 0, 0);
                }
                __builtin_amdgcn_s_setprio(0);
            }
        };
        loadB(B0, 0);
        #pragma unroll 1
        for (int ks = 0; ks < KSTEPS; ks += 2) {
            loadB(B1, ks + 1);
            doK(B0, ks);
            if (ks + 2 < KSTEPS) loadB(B0, ks + 2);
            doK(B1, ks + 1);
        }
        // combine + relu
        #pragma unroll
        for (int mf = 0; mf < 4; ++mf)
            #pragma unroll
            for (int nf = 0; nf < 4; ++nf) {
                f32x4 v;
                #pragma unroll
                for (int e = 0; e < 4; ++e)
                    v[e] = fmaxf(fmaf(accM[mf][nf][e], MINV, accH[mf][nf][e]), 0.f);
                accH[mf][nf] = v;
            }
        // LN stats (rows 0..63)
        #pragma unroll
        for (int mf = 0; mf < 4; ++mf)
            #pragma unroll
            for (int r = 0; r < 4; ++r) {
                float s = (accH[mf][0][r] + accH[mf][1][r]) + (accH[mf][2][r] + accH[mf][3][r]);
                float q = accH[mf][0][r] * accH[mf][0][r];
                q = fmaf(accH[mf][1][r], accH[mf][1][r], q);
                q = fmaf(accH[mf][2][r], accH[mf][2][r], q);
                q = fmaf(accH[mf][3][r], accH[mf][3][r], q);
                #pragma unroll
                for (int o = 1; o < 16; o <<= 1) {
                    s += __shfl_xor(s, o, 64);
                    q += __shfl_xor(q, o, 64);
                }
                if (l15 == 0) {
                    const int idx = mf * 16 + lg * 4 + r;
                    sumS[wid][idx] = s;
                    sumQ[wid][idx] = q;
                }
            }
        __syncthreads();
        {   // redundant per-wave mu/rs, no second barrier (validated R8/R9)
            const int i = lane;
            const float S = (sumS[0][i] + sumS[1][i]) + (sumS[2][i] + sumS[3][i]);
            const float Q = (sumQ[0][i] + sumQ[1][i]) + (sumQ[2][i] + sumQ[3][i]);
            const float mu = S * (1.f / 256.f);
            const float var = fmaf(-mu, mu, Q * (1.f / 256.f));
            muS[i] = mu;
            rsS[i] = 1.0f / sqrtf(var + 1e-6f);
        }
        // normalize in-regs, then dense partial dot -> dsum
        float dv[4];
        #pragma unroll
        for (int nf = 0; nf < 4; ++nf) dv[nf] = dwg[NGc + nf * 16 + l15];
        #pragma unroll
        for (int mf = 0; mf < 4; ++mf)
            #pragma unroll
            for (int r = 0; r < 4; ++r) {
                const int row = mf * 16 + lg * 4 + r;
                const float mu = muS[row];
                const float rs = rsS[row];
                float p = 0.f;
                #pragma unroll
                for (int nf = 0; nf < 4; ++nf) {
                    const float v = (accH[mf][nf][r] - mu) * rs * gv[nf] + bvv[nf];
                    p = fmaf(v, dv[nf], p);
                }
                #pragma unroll
                for (int o = 1; o < 16; o <<= 1) p += __shfl_xor(p, o, 64);
                if (l15 == 0) dsum[wid][row] = p;
            }
        __syncthreads();
        if (tid < 64) {
            const float pd = (dsum[0][tid] + dsum[1][tid]) + (dsum[2][tid] + dsum[3][tid]) + dbg[0];
            const float dcl = fminf(fmaxf(pd, 0.0f), 75.0f);
            durG[b * TT + base + tid] = (int)rintf(dcl);   // RTNE matches jnp.round
        }
    }
}

// ---------------- cumsum + length-regulate gather ----------
// enc loads NORMAL (L2/L3 catch the ~2x source-row reuse); out stores NT.
__global__ __launch_bounds__(256)
void va_gather(const float* __restrict__ enc, const int* __restrict__ durG,
               float* __restrict__ outg)
{
    __shared__ int cumS[TT];
    __shared__ int wtotS[2];
    const int b    = blockIdx.x;
    const int tid  = threadIdx.x;
    const int wid  = tid >> 6;
    const int lane = tid & 63;

    int sv = 0;
    if (tid < TT) {
        sv = durG[b * TT + tid];
        #pragma unroll
        for (int o = 1; o < 64; o <<= 1) {
            const int u = __shfl_up(sv, o, 64);
            if (lane >= o) sv += u;
        }
        if (lane == 63) wtotS[tid >> 6] = sv;
    }
    __syncthreads();
    if (tid < TT) {
        if (tid >= 64) sv += wtotS[0];
        cumS[tid] = sv;
    }
    __syncthreads();

    const int total = cumS[TT - 1];
    const f32x4* encB4 = reinterpret_cast<const f32x4*>(enc) + (size_t)b * (TT * 64);
    f32x4* outB4 = reinterpret_cast<f32x4*>(outg) + (size_t)b * (MAXLEN * 64);
    for (int pp = 0; pp < 20; ++pp) {
        const int p = wid * 20 + pp;     // 4 waves x 20 frames = 80
        int lo = 0, hi = TT;
        while (lo < hi) {                // uniform across the wave
            const int mid = (lo + hi) >> 1;
            if (cumS[mid] <= p) lo = mid + 1; else hi = mid;
        }
        f32x4 v = {0.f, 0.f, 0.f, 0.f};
        if (p < total) {
            const int src = (lo < TT) ? lo : (TT - 1);
            v = encB4[src * 64 + lane];
        }
        __builtin_nontemporal_store(v, &outB4[p * 64 + lane]);
    }
}

extern "C" void kernel_launch(void* const* d_in, const int* in_sizes, int n_in,
                              void* d_out, int out_size, void* d_ws, size_t ws_size,
                              hipStream_t stream) {
    const float* enc = (const float*)d_in[0];
    const float* w1  = (const float*)d_in[1];
    const float* b1  = (const float*)d_in[2];
    const float* w2  = (const float*)d_in[3];
    const float* b2  = (const float*)d_in[4];
    const float* gam = (const float*)d_in[5];
    const float* bet = (const float*)d_in[6];
    const float* dw  = (const float*)d_in[7];
    const float* db  = (const float*)d_in[8];
    float* out = (float*)d_out;

    const int B = in_sizes[0] / (TT * CC);   // 2048
    half8v* wsB = (half8v*)d_ws;                               // 1,572,864 B
    int* durG = (int*)((char*)d_ws + 98304u * 16u);            // B*128*4 B

    hipLaunchKernelGGL(va_prep, dim3(384), dim3(256), 0, stream, w1, w2, wsB);
    hipLaunchKernelGGL(va_conv, dim3(B * 2), dim3(256), 0, stream,
                       enc, b1, b2, gam, bet, dw, db, wsB, durG);
    hipLaunchKernelGGL(va_gather, dim3(B), dim3(256), 0, stream, enc, durG, out);
}

// Round 18
// 620.154 us; speedup vs baseline: 1.0066x; 1.0066x over previous
//
#include <hip/hip_runtime.h>
#include <hip/hip_bf16.h>
#include <math.h>

#define TT 128      // time steps
#define CC 256      // channels
#define MAXLEN 80
#define KSTEPS 24   // 3 taps * 8 k-blocks of 32
#define SLOTS 68    // rows base-2 .. base+65 ; slot = (row-base)+2
#define NCH16 32    // 16B chunks (8 f16) per 256-ch row

typedef __attribute__((ext_vector_type(8))) _Float16 half8v;  // 8 f16 = 4 VGPR
typedef __attribute__((ext_vector_type(2))) _Float16 half2v;
typedef __attribute__((ext_vector_type(4))) float f32x4;

#define MSCALE 4096.0f       // 2^12: keeps m-plane out of f16 denormal range
#define MINV   (1.0f/4096.0f)

__device__ __forceinline__ int chunkidx(int slot, int c16) {
    return slot * NCH16 + (c16 ^ (slot & 7));
}

// h = RTZ f16 pair (pkrtz); m = RTNE f16 of (x-h)*4096 (exact residual capture).
__device__ __forceinline__ void split2(float x0, float x1, half2v& h, half2v& m) {
    h = __builtin_bit_cast(half2v, __builtin_amdgcn_cvt_pkrtz(x0, x1));
    m.x = (_Float16)fmaf((float)h.x, -MSCALE, x0 * MSCALE);
    m.y = (_Float16)fmaf((float)h.y, -MSCALE, x1 * MSCALE);
}

// ---------------- prep: split conv weights into f16 h/m planes (m scaled 2^12,
// both RTNE) in MFMA B-fragment order. frag = (((cv*3+tap)*8+kk2)*2+plane);
// entry idx = (frag*16 + nfg)*64 + lane; each entry = 8 f16 (k-contig).
__global__ void va_prep(const float* __restrict__ w1, const float* __restrict__ w2,
                        half8v* __restrict__ wsB)
{
    const int idx = blockIdx.x * 256 + threadIdx.x;   // 0 .. 98303
    const int lane = idx & 63;
    int q = idx >> 6;
    const int nfg = q & 15;   q >>= 4;
    const int plane = q & 1;  q >>= 1;
    const int kk2 = q & 7;    q >>= 3;
    const int tap = q % 3;
    const int cv  = q / 3;
    const float* w = cv ? w2 : w1;
    const int co  = nfg * 16 + (lane & 15);
    const int ci0 = kk2 * 32 + (lane >> 4) * 8;
    half8v out;
    #pragma unroll
    for (int j = 0; j < 8; ++j) {
        const float x = w[tap * (CC * CC) + (ci0 + j) * CC + co];
        const _Float16 h = (_Float16)x;           // RTNE
        if (plane == 0) out[j] = h;
        else            out[j] = (_Float16)((x - (float)h) * MSCALE);
    }
    wsB[idx] = out;
}

// ---------------- conv kernel: 2 WGs per batch, 64 rows each, 4 waves.
// Wave w owns cols [w*64, w*64+64) (nf=4). conv1 computes x1 rows
// base-1..base+64 via frags {-1,15,31,47,49}; dup rows write identical bits.
__global__ __launch_bounds__(256, 2)
void va_conv(const float* __restrict__ enc,
             const float* __restrict__ b1g, const float* __restrict__ b2g,
             const float* __restrict__ gg,  const float* __restrict__ bbg,
             const float* __restrict__ dwg, const float* __restrict__ dbg,
             const half8v* __restrict__ wsB,
             int* __restrict__ durG)
{
    __shared__ half8v P[2][SLOTS * NCH16];   // 69,632 B
    __shared__ float sumS[4][80];
    __shared__ float sumQ[4][80];
    __shared__ float muS[80];
    __shared__ float rsS[80];
    __shared__ float dsum[4][64];

    const int bb   = blockIdx.x;
    const int b    = bb >> 1;
    const int base = (bb & 1) << 6;     // 0 or 64
    const int tid  = threadIdx.x;
    const int wid  = tid >> 6;          // 0..3
    const int lane = tid & 63;
    const int l15  = lane & 15;
    const int lg   = lane >> 4;
    const int NGc  = wid * 64;          // col base

    const f32x4* encB4 = reinterpret_cast<const f32x4*>(enc) + (size_t)b * (TT * 64);

    // ---- stage enc rows base-2..base+65: NORMAL loads (keep L3 warm for
    // the gather pass), 2-deep software pipeline ----
    {
        const f32x4 z4 = {0.f, 0.f, 0.f, 0.f};
        f32x4 pa[2] = {z4, z4}, pb[2] = {z4, z4};
        {
            const int m2 = tid;
            const int ra = base + (m2 >> 5) - 2;
            if (ra >= 0 && ra < TT) {
                const f32x4* src = encB4 + ra * 64 + (m2 & 31) * 2;
                pa[0] = src[0];
                pb[0] = src[1];
            }
        }
        #pragma unroll
        for (int it = 0; it < 9; ++it) {
            const int nxt = it + 1;
            if (nxt < 9) {
                const int m2 = tid + nxt * 256;
                pa[nxt & 1] = z4; pb[nxt & 1] = z4;
                if (m2 < SLOTS * NCH16) {
                    const int ra = base + (m2 >> 5) - 2;
                    if (ra >= 0 && ra < TT) {
                        const f32x4* src = encB4 + ra * 64 + (m2 & 31) * 2;
                        pa[nxt & 1] = src[0];
                        pb[nxt & 1] = src[1];
                    }
                }
            }
            const int m2 = tid + it * 256;
            if (m2 < SLOTS * NCH16) {
                const f32x4 v0 = pa[it & 1], v1 = pb[it & 1];
                half8v h8, m8;
                half2v hp, mp;
                split2(v0.x, v0.y, hp, mp); h8[0]=hp.x; h8[1]=hp.y; m8[0]=mp.x; m8[1]=mp.y;
                split2(v0.z, v0.w, hp, mp); h8[2]=hp.x; h8[3]=hp.y; m8[2]=mp.x; m8[3]=mp.y;
                split2(v1.x, v1.y, hp, mp); h8[4]=hp.x; h8[5]=hp.y; m8[4]=mp.x; m8[5]=mp.y;
                split2(v1.z, v1.w, hp, mp); h8[6]=hp.x; h8[7]=hp.y; m8[6]=mp.x; m8[7]=mp.y;
                const int ci = chunkidx(m2 >> 5, m2 & 31);
                P[0][ci] = h8;
                P[1][ci] = m8;
            }
        }
    }
    __syncthreads();

    float gv[4], bvv[4];
    #pragma unroll
    for (int nf = 0; nf < 4; ++nf) {
        gv[nf]  = gg[NGc + nf * 16 + l15];
        bvv[nf] = bbg[NGc + nf * 16 + l15];
    }

    f32x4 accH[5][4];
    f32x4 accM[5][4];

    // ================= conv1: 5 frags {-1,15,31,47,49}, dbuf B =========
    {
        #pragma unroll
        for (int nf = 0; nf < 4; ++nf) {
            const float bz = b1g[NGc + nf * 16 + l15];
            const f32x4 b4 = {bz, bz, bz, bz};
            const f32x4 z4 = {0.f, 0.f, 0.f, 0.f};
            #pragma unroll
            for (int mf = 0; mf < 5; ++mf) { accH[mf][nf] = b4; accM[mf][nf] = z4; }
        }
        half8v B0[8], B1[8];   // [plane*4 + nf]
        auto loadB1 = [&](half8v (&Bp)[8], int ks) {
            const int tap = ks >> 3, kk2 = ks & 7;
            const int fb = (tap * 8 + kk2) * 2;          // cv=0
            #pragma unroll
            for (int p = 0; p < 2; ++p)
                #pragma unroll
                for (int nf = 0; nf < 4; ++nf)
                    Bp[p * 4 + nf] = wsB[(size_t)((fb + p) * 16 + (wid * 4 + nf)) * 64 + lane];
        };
        auto doK1 = [&](const half8v (&Bp)[8], int ks) {
            const int tap = ks >> 3, kk2 = ks & 7;
            #pragma unroll
            for (int mf = 0; mf < 5; ++mf) {
                constexpr int F1[5] = {-1, 15, 31, 47, 49};
                const int slot = F1[mf] + l15 + tap + 1;   // (row-1+tap)+2
                const int ci = chunkidx(slot, kk2 * 4 + lg);
                const half8v Ah = P[0][ci];
                const half8v Am = P[1][ci];
                __builtin_amdgcn_s_setprio(1);             // T5: favor MFMA wave
                #pragma unroll
                for (int nf = 0; nf < 4; ++nf) {
                    accH[mf][nf] = __builtin_amdgcn_mfma_f32_16x16x32_f16(Ah, Bp[nf],     accH[mf][nf], 0, 0, 0);
                    accM[mf][nf] = __builtin_amdgcn_mfma_f32_16x16x32_f16(Ah, Bp[4 + nf], accM[mf][nf], 0, 0, 0);
                    accM[mf][nf] = __builtin_amdgcn_mfma_f32_16x16x32_f16(Am, Bp[nf],     accM[mf][nf], 0, 0, 0);
                }
                __builtin_amdgcn_s_setprio(0);
            }
        };
        loadB1(B0, 0);
        #pragma unroll 1
        for (int ks = 0; ks < KSTEPS; ks += 2) {
            loadB1(B1, ks + 1);
            doK1(B0, ks);
            if (ks + 2 < KSTEPS) loadB1(B0, ks + 2);
            doK1(B1, ks + 1);
        }
        // combine + relu
        #pragma unroll
        for (int mf = 0; mf < 5; ++mf)
            #pragma unroll
            for (int nf = 0; nf < 4; ++nf) {
                f32x4 v;
                #pragma unroll
                for (int e = 0; e < 4; ++e)
                    v[e] = fmaxf(fmaf(accM[mf][nf][e], MINV, accH[mf][nf][e]), 0.f);
                accH[mf][nf] = v;
            }
        // LN single-pass stats (rows idx = row+1 in [0,65]; dup rows write
        // bitwise-identical values -> benign)
        constexpr int F1c[5] = {-1, 15, 31, 47, 49};
        #pragma unroll
        for (int mf = 0; mf < 5; ++mf)
            #pragma unroll
            for (int r = 0; r < 4; ++r) {
                float s = (accH[mf][0][r] + accH[mf][1][r]) + (accH[mf][2][r] + accH[mf][3][r]);
                float q = accH[mf][0][r] * accH[mf][0][r];
                q = fmaf(accH[mf][1][r], accH[mf][1][r], q);
                q = fmaf(accH[mf][2][r], accH[mf][2][r], q);
                q = fmaf(accH[mf][3][r], accH[mf][3][r], q);
                #pragma unroll
                for (int o = 1; o < 16; o <<= 1) {
                    s += __shfl_xor(s, o, 64);
                    q += __shfl_xor(q, o, 64);
                }
                if (l15 == 0) {
                    const int idx = F1c[mf] + lg * 4 + r + 1;
                    sumS[wid][idx] = s;
                    sumQ[wid][idx] = q;
                }
            }
        __syncthreads();
        // redundant per-wave mu/rs for all 66 rows (identical bits from all
        // writers; within-wave RAW ordered by lgkmcnt) — validated R8/R9
        for (int i = lane; i < 66; i += 64) {
            const float S = (sumS[0][i] + sumS[1][i]) + (sumS[2][i] + sumS[3][i]);
            const float Q = (sumQ[0][i] + sumQ[1][i]) + (sumQ[2][i] + sumQ[3][i]);
            const float mu = S * (1.f / 256.f);
            const float var = fmaf(-mu, mu, Q * (1.f / 256.f));
            muS[i] = mu;
            rsS[i] = 1.0f / sqrtf(var + 1e-6f);
        }
        // normalize + writeback x1 (h/m planes); rows outside [0,TT) forced 0
        _Float16* Ph = (_Float16*)&P[0][0];
        _Float16* Pm = (_Float16*)&P[1][0];
        #pragma unroll
        for (int mf = 0; mf < 5; ++mf)
            #pragma unroll
            for (int r = 0; r < 4; ++r) {
                const int row = F1c[mf] + lg * 4 + r;
                const float mu = muS[row + 1];
                const float rs = rsS[row + 1];
                const bool valid = (base + row >= 0) && (base + row < TT);
                #pragma unroll
                for (int nf = 0; nf < 4; ++nf) {
                    float v = (accH[mf][nf][r] - mu) * rs * gv[nf] + bvv[nf];
                    if (!valid) v = 0.f;
                    const int col = NGc + nf * 16 + l15;
                    const int off = chunkidx(row + 2, col >> 3) * 8 + (col & 7);
                    const _Float16 h = (_Float16)v;   // RTNE
                    Ph[off] = h;
                    Pm[off] = (_Float16)fmaf((float)h, -MSCALE, v * MSCALE);
                }
            }
    }
    __syncthreads();

    // ================= conv2: 4 frags {0,16,32,48}, dbuf B ==============
    {
        #pragma unroll
        for (int nf = 0; nf < 4; ++nf) {
            const float bz = b2g[NGc + nf * 16 + l15];
            const f32x4 b4 = {bz, bz, bz, bz};
            const f32x4 z4 = {0.f, 0.f, 0.f, 0.f};
            #pragma unroll
            for (int mf = 0; mf < 4; ++mf) { accH[mf][nf] = b4; accM[mf][nf] = z4; }
        }
        half8v B0[8], B1[8];
        auto loadB = [&](half8v (&Bp)[8], int ks) {
            const int tap = ks >> 3, kk2 = ks & 7;
            const int fb = ((3 + tap) * 8 + kk2) * 2;    // cv=1
            #pragma unroll
            for (int p = 0; p < 2; ++p)
                #pragma unroll
                for (int nf = 0; nf < 4; ++nf)
                    Bp[p * 4 + nf] = wsB[(size_t)((fb + p) * 16 + (wid * 4 + nf)) * 64 + lane];
        };
        auto doK = [&](const half8v (&Bp)[8], int ks) {
            const int tap = ks >> 3, kk2 = ks & 7;
            #pragma unroll
            for (int mf = 0; mf < 4; ++mf) {
                const int slot = mf * 16 + l15 + tap + 1;
                const int ci = chunkidx(slot, kk2 * 4 + lg);
                const half8v Ah = P[0][ci];
                const half8v Am = P[1][ci];
                __builtin_amdgcn_s_setprio(1);             // T5
                #pragma unroll
                for (int nf = 0; nf < 4; ++nf) {
                    accH[mf][nf] = __builtin_amdgcn_mfma_f32_16x16x32_f16(Ah, Bp[nf],     accH[mf][nf], 0, 0, 0);
                    accM[mf][nf] = __builtin_amdgcn_mfma_f32_16x16x32_f16(Ah, Bp[4 + nf], accM[mf][nf], 0, 0, 0);
                    accM[mf][nf] = __builtin_amdgcn_mfma_f32_16x16x32_f16(Am, Bp[nf],     accM[mf][nf], 0, 0, 0);
                }
                __builtin_amdgcn_s_setprio(0);
            }
        };
        loadB(B0, 0);
        #pragma unroll 1
        for (int ks = 0; ks < KSTEPS; ks += 2) {
            loadB(B1, ks + 1);
            doK(B0, ks);
            if (ks + 2 < KSTEPS) loadB(B0, ks + 2);
            doK(B1, ks + 1);
        }
        // combine + relu
        #pragma unroll
        for (int mf = 0; mf < 4; ++mf)
            #pragma unroll
            for (int nf = 0; nf < 4; ++nf) {
                f32x4 v;
                #pragma unroll
                for (int e = 0; e < 4; ++e)
                    v[e] = fmaxf(fmaf(accM[mf][nf][e], MINV, accH[mf][nf][e]), 0.f);
                accH[mf][nf] = v;
            }
        // LN stats (rows 0..63)
        #pragma unroll
        for (int mf = 0; mf < 4; ++mf)
            #pragma unroll
            for (int r = 0; r < 4; ++r) {
                float s = (accH[mf][0][r] + accH[mf][1][r]) + (accH[mf][2][r] + accH[mf][3][r]);
                float q = accH[mf][0][r] * accH[mf][0][r];
                q = fmaf(accH[mf][1][r], accH[mf][1][r], q);
                q = fmaf(accH[mf][2][r], accH[mf][2][r], q);
                q = fmaf(accH[mf][3][r], accH[mf][3][r], q);
                #pragma unroll
                for (int o = 1; o < 16; o <<= 1) {
                    s += __shfl_xor(s, o, 64);
                    q += __shfl_xor(q, o, 64);
                }
                if (l15 == 0) {
                    const int idx = mf * 16 + lg * 4 + r;
                    sumS[wid][idx] = s;
                    sumQ[wid][idx] = q;
                }
            }
        __syncthreads();
        {   // redundant per-wave mu/rs, no second barrier (validated R8/R9)
            const int i = lane;
            const float S = (sumS[0][i] + sumS[1][i]) + (sumS[2][i] + sumS[3][i]);
            const float Q = (sumQ[0][i] + sumQ[1][i]) + (sumQ[2][i] + sumQ[3][i]);
            const float mu = S * (1.f / 256.f);
            const float var = fmaf(-mu, mu, Q * (1.f / 256.f));
            muS[i] = mu;
            rsS[i] = 1.0f / sqrtf(var + 1e-6f);
        }
        // normalize in-regs, then dense partial dot -> dsum
        float dv[4];
        #pragma unroll
        for (int nf = 0; nf < 4; ++nf) dv[nf] = dwg[NGc + nf * 16 + l15];
        #pragma unroll
        for (int mf = 0; mf < 4; ++mf)
            #pragma unroll
            for (int r = 0; r < 4; ++r) {
                const int row = mf * 16 + lg * 4 + r;
                const float mu = muS[row];
                const float rs = rsS[row];
                float p = 0.f;
                #pragma unroll
                for (int nf = 0; nf < 4; ++nf) {
                    const float v = (accH[mf][nf][r] - mu) * rs * gv[nf] + bvv[nf];
                    p = fmaf(v, dv[nf], p);
                }
                #pragma unroll
                for (int o = 1; o < 16; o <<= 1) p += __shfl_xor(p, o, 64);
                if (l15 == 0) dsum[wid][row] = p;
            }
        __syncthreads();
        if (tid < 64) {
            const float pd = (dsum[0][tid] + dsum[1][tid]) + (dsum[2][tid] + dsum[3][tid]) + dbg[0];
            const float dcl = fminf(fmaxf(pd, 0.0f), 75.0f);
            durG[b * TT + base + tid] = (int)rintf(dcl);   // RTNE matches jnp.round
        }
    }
}

// ---------------- cumsum + length-regulate gather ----------
// enc loads NORMAL (L2/L3 catch the ~2x source-row reuse); out stores NT.
__global__ __launch_bounds__(256)
void va_gather(const float* __restrict__ enc, const int* __restrict__ durG,
               float* __restrict__ outg)
{
    __shared__ int cumS[TT];
    __shared__ int wtotS[2];
    const int b    = blockIdx.x;
    const int tid  = threadIdx.x;
    const int wid  = tid >> 6;
    const int lane = tid & 63;

    int sv = 0;
    if (tid < TT) {
        sv = durG[b * TT + tid];
        #pragma unroll
        for (int o = 1; o < 64; o <<= 1) {
            const int u = __shfl_up(sv, o, 64);
            if (lane >= o) sv += u;
        }
        if (lane == 63) wtotS[tid >> 6] = sv;
    }
    __syncthreads();
    if (tid < TT) {
        if (tid >= 64) sv += wtotS[0];
        cumS[tid] = sv;
    }
    __syncthreads();

    const int total = cumS[TT - 1];
    const f32x4* encB4 = reinterpret_cast<const f32x4*>(enc) + (size_t)b * (TT * 64);
    f32x4* outB4 = reinterpret_cast<f32x4*>(outg) + (size_t)b * (MAXLEN * 64);
    for (int pp = 0; pp < 20; ++pp) {
        const int p = wid * 20 + pp;     // 4 waves x 20 frames = 80
        int lo = 0, hi = TT;
        while (lo < hi) {                // uniform across the wave
            const int mid = (lo + hi) >> 1;
            if (cumS[mid] <= p) lo = mid + 1; else hi = mid;
        }
        f32x4 v = {0.f, 0.f, 0.f, 0.f};
        if (p < total) {
            const int src = (lo < TT) ? lo : (TT - 1);
            v = encB4[src * 64 + lane];
        }
        __builtin_nontemporal_store(v, &outB4[p * 64 + lane]);
    }
}

extern "C" void kernel_launch(void* const* d_in, const int* in_sizes, int n_in,
                              void* d_out, int out_size, void* d_ws, size_t ws_size,
                              hipStream_t stream) {
    const float* enc = (const float*)d_in[0];
    const float* w1  = (const float*)d_in[1];
    const float* b1  = (const float*)d_in[2];
    const float* w2  = (const float*)d_in[3];
    const float* b2  = (const float*)d_in[4];
    const float* gam = (const float*)d_in[5];
    const float* bet = (const float*)d_in[6];
    const float* dw  = (const float*)d_in[7];
    const float* db  = (const float*)d_in[8];
    float* out = (float*)d_out;

    const int B = in_sizes[0] / (TT * CC);   // 2048
    half8v* wsB = (half8v*)d_ws;                               // 1,572,864 B
    int* durG = (int*)((char*)d_ws + 98304u * 16u);            // B*128*4 B

    hipLaunchKernelGGL(va_prep, dim3(384), dim3(256), 0, stream, w1, w2, wsB);
    hipLaunchKernelGGL(va_conv, dim3(B * 2), dim3(256), 0, stream,
                       enc, b1, b2, gam, bet, dw, db, wsB, durG);
    hipLaunchKernelGGL(va_gather, dim3(B), dim3(256), 0, stream, enc, durG, out);
}